// Round 12
// baseline (16360.184 us; speedup 1.0000x reference)
//
#include <hip/hip_runtime.h>
#include <hip/hip_bf16.h>

#define B_   32
#define TIN  16
#define X_   8192
#define H_   64
#define F_   128
#define K_   5
#define DEPTH 3
#define TOUT 32
#define TILE 32           // one wave per block, 2 col-groups of 16
#define PROW (X_ + 4)     // padded rows per batch: 2 zero | X | 2 zero

typedef __attribute__((ext_vector_type(8))) _Float16 h16x8;
typedef __attribute__((ext_vector_type(4))) _Float16 h16x4;
typedef __attribute__((ext_vector_type(4))) float f32x4;

// GELU via A&S 7.1.25 3-term erf (|eps| <= 2.5e-5), branch-free
__device__ __forceinline__ float gelu_fast(float z) {
    float t = fminf(fabsf(z) * 0.70710678118654752f, 3.9192f);
    float w = __builtin_amdgcn_rcpf(__builtin_fmaf(0.47047f, t, 1.0f));
    float p = w * __builtin_fmaf(w, __builtin_fmaf(w, 0.7478556f, -0.0958798f), 0.3480242f);
    float e = __expf(-t * t);
    float erf_abs = __builtin_fmaf(-p, e, 1.0f);
    return 0.5f * z * (1.0f + copysignf(erf_abs, z));
}

// swizzled LDS address: row stride rb bytes, XOR (row&7)<<4 spreads banks
__device__ __forceinline__ char* lp(void* base, int row, int cb, int rb) {
    return (char*)base + row * rb + (cb ^ ((row & 7) << 4));
}
// 16x32 activation fragment from swizzled LDS (B role): lane -> (x=row, d=kt*32+l4*8+e)
__device__ __forceinline__ h16x8 lda(const void* base, int row, int kt, int rb, int lane) {
    return *(const h16x8*)((const char*)base + row * rb +
                           ((kt * 64 + ((lane >> 4) << 4)) ^ ((row & 7) << 4)));
}
// packed weight fragments: contiguous per fragment, fully coalesced wave reads
__device__ __forceinline__ h16x4 ldp16(const _Float16* w, int frag, int lane) {
    return *(const h16x4*)&w[(frag << 8) + (lane << 2)];
}
__device__ __forceinline__ h16x8 ldp32(const _Float16* w, int frag, int lane) {
    return *(const h16x8*)&w[(frag << 9) + (lane << 3)];
}

__device__ __forceinline__ f32x4 mfma32(h16x8 a, h16x8 b, f32x4 c) {
    return __builtin_amdgcn_mfma_f32_16x16x32_f16(a, b, c, 0, 0, 0);
}
__device__ __forceinline__ f32x4 mfma16(h16x4 a, h16x4 b, f32x4 c) {
    return __builtin_amdgcn_mfma_f32_16x16x16f16(a, b, c, 0, 0, 0);
}

// ---------------- weight prep: fp32 -> packed fp16 fragments ----------------
__global__ __launch_bounds__(256) void k_prep_conv(const float* __restrict__ s,
                                                   _Float16* __restrict__ w) {
    int t = blockIdx.x * 256 + threadIdx.x;
    if (t >= DEPTH * 20480) return;
    int i = t / 20480, r = t % 20480;
    int frag = r >> 9, lane = (r >> 3) & 63, e = r & 7;
    int k = frag >> 3, kt = (frag >> 2) & 1, nt = frag & 3;
    int o = nt * 16 + (lane & 15);
    int d = kt * 32 + ((lane >> 4) << 3) + e;
    w[t] = (_Float16)s[((i * 64 + o) * 64 + d) * 5 + k];
}
__global__ __launch_bounds__(256) void k_pack16(const float* __restrict__ s,
                                                _Float16* __restrict__ w,
                                                int NT, int KT, int K, int total) {
    int t = blockIdx.x * 256 + threadIdx.x;
    if (t >= total) return;
    int per = NT * KT * 256;
    int li = t / per, r = t % per;
    int frag = r >> 8, lane = (r >> 2) & 63, e = r & 3;
    int kt = frag / NT, nt = frag % NT;
    int n = nt * 16 + (lane & 15);
    int kk = kt * 16 + ((lane >> 4) << 2) + e;
    w[t] = (_Float16)s[li * (NT * 16 * K) + n * K + kk];
}

// zero the halo pad rows of both psi buffers (rows 0,1 and X+2,X+3 per batch)
__global__ __launch_bounds__(256) void k_zero_pads(_Float16* __restrict__ pA,
                                                   _Float16* __restrict__ pB) {
    int i = blockIdx.x * 256 + threadIdx.x;      // over B*4*64
    if (i >= B_ * 4 * 64) return;
    int b = i >> 8, r = (i >> 6) & 3, h = i & 63;
    int row = (r < 2) ? r : (X_ + r);            // 0,1,X+2,X+3
    size_t off = ((size_t)b * PROW + row) * H_ + h;
    pA[off] = (_Float16)0.f;
    pB[off] = (_Float16)0.f;
}

// ---------------- encoder (runs once; fp32 VALU, writes fp16 padded psi) ----------------
__global__ __launch_bounds__(256) void k_encoder(const float* __restrict__ xin,
                                                 const float* __restrict__ enc_w,
                                                 const float* __restrict__ enc_b,
                                                 _Float16* __restrict__ psi) {
    const int b  = blockIdx.y;
    const int x0 = blockIdx.x * 64;
    __shared__ float s_x[TIN][64];
    __shared__ float s_w[TIN][H_];
    __shared__ float s_p[64][H_];
    const int tid = threadIdx.x;

    for (int idx = tid; idx < TIN * 64; idx += 256) {
        int t = idx >> 6, xl = idx & 63;
        s_x[t][xl] = xin[((size_t)b * TIN + t) * X_ + x0 + xl];
    }
    for (int idx = tid; idx < TIN * H_; idx += 256) {
        int t = idx >> 6, h = idx & 63;
        s_w[t][h] = enc_w[h * TIN + t];
    }
    __syncthreads();
    {
        int h = tid & 63, grp = tid >> 6;
        float bias = enc_b[h];
        for (int r = 0; r < 16; ++r) {
            int xl = grp * 16 + r;
            float acc = bias;
            #pragma unroll
            for (int t = 0; t < TIN; ++t) acc += s_x[t][xl] * s_w[t][h];
            s_p[xl][h] = acc;
        }
    }
    __syncthreads();
    {
        int lane = tid & 63, wv = tid >> 6;
        for (int r = 0; r < 16; ++r) {
            int xl = wv * 16 + r;
            float v = s_p[xl][lane];
            float s = v;
            #pragma unroll
            for (int off = 32; off; off >>= 1) s += __shfl_xor(s, off);
            float mu = s * (1.0f / 64.0f);
            float dv = v - mu;
            float q = dv * dv;
            #pragma unroll
            for (int off = 32; off; off >>= 1) q += __shfl_xor(q, off);
            float sd = sqrtf(q * (1.0f / 63.0f)) + 1e-6f;
            psi[((size_t)b * PROW + 2 + x0 + xl) * H_ + lane] = (_Float16)(dv / sd);
        }
    }
}

// ---------------- fused layer: ONE WAVE PER BLOCK, zero barriers ----------------
// psi fp16 padded [b][2|X|2][64]. Each wave stages its own 36-row halo tile
// (4.6 KB LDS; same-wave ds ordering, no __syncthreads anywhere). Register
// chain conv->mlp1->mlp2->LN(->dec head), operand-swapped (D[ch][x] = W.act).
// 32 independent waves/CU can be resident -> natural phase desync hides latency.
__global__ __launch_bounds__(64, 8) void k_layer(const _Float16* __restrict__ pin,
                                                 _Float16* __restrict__ pout,
                                                 const _Float16* __restrict__ cw,
                                                 const float* __restrict__ cb,
                                                 const _Float16* __restrict__ w1,
                                                 const float* __restrict__ b1,
                                                 const _Float16* __restrict__ w2,
                                                 const float* __restrict__ b2,
                                                 const float* __restrict__ g,
                                                 const float* __restrict__ bt,
                                                 const _Float16* __restrict__ d1,
                                                 const float* __restrict__ b1d,
                                                 const float* __restrict__ w2d,
                                                 const float* __restrict__ b2d,
                                                 float* __restrict__ yout, int step) {
    __shared__ __align__(16) _Float16 sA[(TILE + 4) * 64];   // 36 rows x 128B = 4.6 KB

    const int lane = threadIdx.x;            // 64-thread block = one wave
    const int b    = blockIdx.y;
    const int x0   = blockIdx.x * TILE;
    const int l15  = lane & 15, l4 = lane >> 4;
    const int xg0  = x0 + l15;

    // ---- stage psi padded rows [x0, x0+36) = global x [x0-2, x0+34), 16B chunks
    {
        const _Float16* src = pin + ((size_t)b * PROW + x0) * H_;
        #pragma unroll
        for (int it = 0; it < 5; ++it) {
            int idx = it * 64 + lane;
            if (idx < (TILE + 4) * 8) {
                int r = idx >> 3, c8 = idx & 7;
                h16x8 v = *(const h16x8*)(src + r * H_ + c8 * 8);
                *(h16x8*)lp(sA, r, c8 * 16, 128) = v;
            }
        }
    }
    // no barrier: single wave, ds ordering via lgkmcnt

    // ---- conv (K=32, swapped): acc[ch][x] over 5 shifts; weights shared by both cgs
    f32x4 acc0[4], acc1[4];
    #pragma unroll
    for (int nt = 0; nt < 4; ++nt) {
        acc0[nt] = *(const f32x4*)&cb[nt * 16 + (l4 << 2)];
        acc1[nt] = acc0[nt];
    }
    #pragma unroll
    for (int k = 0; k < K_; ++k) {
        h16x8 b00 = lda(sA, l15 + k,      0, 128, lane);
        h16x8 b01 = lda(sA, l15 + k,      1, 128, lane);
        h16x8 b10 = lda(sA, 16 + l15 + k, 0, 128, lane);
        h16x8 b11 = lda(sA, 16 + l15 + k, 1, 128, lane);
        #pragma unroll
        for (int nt = 0; nt < 4; ++nt) {
            h16x8 a0 = ldp32(cw, (k * 2 + 0) * 4 + nt, lane);
            h16x8 a1 = ldp32(cw, (k * 2 + 1) * 4 + nt, lane);
            acc0[nt] = mfma32(a0, b00, acc0[nt]);
            acc1[nt] = mfma32(a0, b10, acc1[nt]);
            acc0[nt] = mfma32(a1, b01, acc0[nt]);
            acc1[nt] = mfma32(a1, b11, acc1[nt]);
        }
    }
    h16x4 hb0[4], hb1[4];
    #pragma unroll
    for (int nt = 0; nt < 4; ++nt) {
        #pragma unroll
        for (int j = 0; j < 4; ++j) {
            hb0[nt][j] = (_Float16)acc0[nt][j];
            hb1[nt][j] = (_Float16)acc1[nt][j];
        }
    }

    // ---- mlp1 (K=16, swapped): m[f][x] = W1 . h
    f32x4 m0[8], m1[8];
    #pragma unroll
    for (int ft = 0; ft < 8; ++ft) {
        m0[ft] = *(const f32x4*)&b1[ft * 16 + (l4 << 2)];
        m1[ft] = m0[ft];
    }
    #pragma unroll
    for (int kt = 0; kt < 4; ++kt) {
        #pragma unroll
        for (int ft = 0; ft < 8; ++ft) {
            h16x4 aw = ldp16(w1, kt * 8 + ft, lane);
            m0[ft] = mfma16(aw, hb0[kt], m0[ft]);
            m1[ft] = mfma16(aw, hb1[kt], m1[ft]);
        }
    }
    h16x4 mb0[8], mb1[8];
    #pragma unroll
    for (int ft = 0; ft < 8; ++ft) {
        #pragma unroll
        for (int j = 0; j < 4; ++j) {
            mb0[ft][j] = (_Float16)gelu_fast(m0[ft][j]);
            mb1[ft][j] = (_Float16)gelu_fast(m1[ft][j]);
        }
    }

    // ---- residual prefetch (fp16 psi, exact same values MFMA consumed)
    const _Float16* pr0 = pin + ((size_t)b * PROW + 2 + xg0) * H_ + (l4 << 2);
    const _Float16* pr1 = pr0 + 16 * H_;
    f32x4 res0[4], res1[4];
    #pragma unroll
    for (int nt = 0; nt < 4; ++nt) {
        h16x4 r0 = *(const h16x4*)(pr0 + nt * 16);
        h16x4 r1 = *(const h16x4*)(pr1 + nt * 16);
        #pragma unroll
        for (int j = 0; j < 4; ++j) { res0[nt][j] = (float)r0[j]; res1[nt][j] = (float)r1[j]; }
    }

    // ---- mlp2 (K=16, swapped): o[d][x] = W2 . m
    f32x4 o0[4], o1[4];
    #pragma unroll
    for (int nt = 0; nt < 4; ++nt) {
        o0[nt] = *(const f32x4*)&b2[nt * 16 + (l4 << 2)];
        o1[nt] = o0[nt];
    }
    #pragma unroll
    for (int kt = 0; kt < 8; ++kt) {
        #pragma unroll
        for (int nt = 0; nt < 4; ++nt) {
            h16x4 aw = ldp16(w2, kt * 4 + nt, lane);
            o0[nt] = mfma16(aw, mb0[kt], o0[nt]);
            o1[nt] = mfma16(aw, mb1[kt], o1[nt]);
        }
    }

    // ---- residual + LN + clip + fp16 store; ps regs feed dec head
    _Float16* pw0 = pout + ((size_t)b * PROW + 2 + xg0) * H_ + (l4 << 2);
    _Float16* pw1 = pw0 + 16 * H_;
    h16x4 ps0[4], ps1[4];
#define LN_CG(OACC, RES, PW, PS)                                               \
    {                                                                          \
        float v[4][4];                                                         \
        float s = 0.f;                                                         \
        _Pragma("unroll")                                                      \
        for (int nt = 0; nt < 4; ++nt) {                                       \
            _Pragma("unroll")                                                  \
            for (int j = 0; j < 4; ++j) {                                      \
                v[nt][j] = OACC[nt][j] + RES[nt][j]; s += v[nt][j];            \
            }                                                                  \
        }                                                                      \
        s += __shfl_xor(s, 16); s += __shfl_xor(s, 32);                        \
        float mu = s * (1.0f / 64.0f);                                         \
        float q = 0.f;                                                         \
        _Pragma("unroll")                                                      \
        for (int nt = 0; nt < 4; ++nt) {                                       \
            _Pragma("unroll")                                                  \
            for (int j = 0; j < 4; ++j) { v[nt][j] -= mu; q += v[nt][j] * v[nt][j]; } \
        }                                                                      \
        q += __shfl_xor(q, 16); q += __shfl_xor(q, 32);                        \
        float rs = rsqrtf(q * (1.0f / 64.0f) + 1e-5f);                         \
        _Pragma("unroll")                                                      \
        for (int nt = 0; nt < 4; ++nt) {                                       \
            f32x4 gg = *(const f32x4*)&g[nt * 16 + (l4 << 2)];                 \
            f32x4 bb = *(const f32x4*)&bt[nt * 16 + (l4 << 2)];                \
            _Pragma("unroll")                                                  \
            for (int j = 0; j < 4; ++j) {                                      \
                float o = v[nt][j] * rs * gg[j] + bb[j];                       \
                o = fminf(10.0f, fmaxf(-10.0f, o));                            \
                PS[nt][j] = (_Float16)o;                                       \
            }                                                                  \
            *(h16x4*)(PW + nt * 16) = PS[nt];                                  \
        }                                                                      \
    }
    LN_CG(o0, res0, pw0, ps0)
    LN_CG(o1, res1, pw1, ps1)
#undef LN_CG

    // ---- fused decoder head (depth 2 only)
    if (yout) {
        f32x4 d0[4], dd1[4];
        #pragma unroll
        for (int ht = 0; ht < 4; ++ht) {
            d0[ht] = *(const f32x4*)&b1d[ht * 16 + (l4 << 2)];
            dd1[ht] = d0[ht];
        }
        #pragma unroll
        for (int kt = 0; kt < 4; ++kt) {
            #pragma unroll
            for (int ht = 0; ht < 4; ++ht) {
                h16x4 aw = ldp16(d1, kt * 4 + ht, lane);
                d0[ht]  = mfma16(aw, ps0[kt], d0[ht]);
                dd1[ht] = mfma16(aw, ps1[kt], dd1[ht]);
            }
        }
        float y0 = 0.f, y1 = 0.f;
        #pragma unroll
        for (int ht = 0; ht < 4; ++ht) {
            f32x4 wq = *(const f32x4*)&w2d[ht * 16 + (l4 << 2)];
            #pragma unroll
            for (int j = 0; j < 4; ++j) {
                y0 += gelu_fast(d0[ht][j])  * wq[j];
                y1 += gelu_fast(dd1[ht][j]) * wq[j];
            }
        }
        y0 += __shfl_xor(y0, 16); y0 += __shfl_xor(y0, 32);
        y1 += __shfl_xor(y1, 16); y1 += __shfl_xor(y1, 32);
        if (l4 == 0) {
            size_t ybase = ((size_t)b * TOUT + step) * X_;
            yout[ybase + xg0]      = y0 + b2d[0];
            yout[ybase + xg0 + 16] = y1 + b2d[0];
        }
    }
}

extern "C" void kernel_launch(void* const* d_in, const int* in_sizes, int n_in,
                              void* d_out, int out_size, void* d_ws, size_t ws_size,
                              hipStream_t stream) {
    const float* xin    = (const float*)d_in[0];
    const float* enc_w  = (const float*)d_in[1];
    const float* enc_b  = (const float*)d_in[2];
    const float* conv_w = (const float*)d_in[3];
    const float* conv_b = (const float*)d_in[4];
    const float* mlp_w1 = (const float*)d_in[5];
    const float* mlp_b1 = (const float*)d_in[6];
    const float* mlp_w2 = (const float*)d_in[7];
    const float* mlp_b2 = (const float*)d_in[8];
    const float* ln_g   = (const float*)d_in[9];
    const float* ln_b   = (const float*)d_in[10];
    const float* dec_w1 = (const float*)d_in[11];
    const float* dec_b1 = (const float*)d_in[12];
    const float* dec_w2 = (const float*)d_in[13];
    const float* dec_b2 = (const float*)d_in[14];
    float* out = (float*)d_out;

    const size_t PSI = (size_t)B_ * PROW * H_;       // fp16 elements
    _Float16* psiA = (_Float16*)d_ws;
    _Float16* psiB = psiA + PSI;
    _Float16* cwf = psiB + PSI;               // [3][40 frags][512]
    _Float16* w1f = cwf + 61440;              // [3][32 frags][256]
    _Float16* w2f = w1f + 24576;              // [3][32 frags][256]
    _Float16* d1f = w2f + 24576;              // [16 frags][256]
    (void)ws_size; (void)n_in; (void)in_sizes; (void)out_size;

    k_zero_pads<<<32, 256, 0, stream>>>(psiA, psiB);
    k_prep_conv<<<240, 256, 0, stream>>>(conv_w, cwf);
    k_pack16<<<96, 256, 0, stream>>>(mlp_w1, w1f, 8, 4, 64, 24576);
    k_pack16<<<96, 256, 0, stream>>>(mlp_w2, w2f, 4, 8, 128, 24576);
    k_pack16<<<16, 256, 0, stream>>>(dec_w1, d1f, 4, 4, 64, 4096);

    k_encoder<<<dim3(X_ / 64, B_), 256, 0, stream>>>(xin, enc_w, enc_b, psiA);

    const _Float16* cur = psiA;
    _Float16* nxt = psiB;
    for (int t = 0; t < TOUT; ++t) {
        for (int i = 0; i < DEPTH; ++i) {
            float* yout = (i == DEPTH - 1) ? out : nullptr;
            k_layer<<<dim3(X_ / TILE, B_), 64, 0, stream>>>(
                cur, nxt,
                cwf + i * 20480, conv_b + i * H_,
                w1f + i * 8192,  mlp_b1 + i * F_,
                w2f + i * 8192,  mlp_b2 + i * H_,
                ln_g + i * H_, ln_b + i * H_,
                d1f, dec_b1, dec_w2, dec_b2, yout, t);
            _Float16* tmp = (_Float16*)cur; cur = nxt; nxt = tmp;
        }
    }
}

// Round 13
// 7066.190 us; speedup vs baseline: 2.3153x; 2.3153x over previous
//
#include <hip/hip_runtime.h>
#include <hip/hip_bf16.h>

#define B_   32
#define TIN  16
#define X_   8192
#define H_   64
#define F_   128
#define K_   5
#define DEPTH 3
#define TOUT 32
#define TILE 128          // 4 waves x 32 x-columns (2 col-groups each)
#define PROW (X_ + 4)     // padded rows per batch: 2 zero | X | 2 zero

typedef __attribute__((ext_vector_type(8))) _Float16 h16x8;
typedef __attribute__((ext_vector_type(4))) _Float16 h16x4;
typedef __attribute__((ext_vector_type(4))) float f32x4;

// GELU via A&S 7.1.25 3-term erf (|eps| <= 2.5e-5), branch-free
__device__ __forceinline__ float gelu_fast(float z) {
    float t = fminf(fabsf(z) * 0.70710678118654752f, 3.9192f);
    float w = __builtin_amdgcn_rcpf(__builtin_fmaf(0.47047f, t, 1.0f));
    float p = w * __builtin_fmaf(w, __builtin_fmaf(w, 0.7478556f, -0.0958798f), 0.3480242f);
    float e = __expf(-t * t);
    float erf_abs = __builtin_fmaf(-p, e, 1.0f);
    return 0.5f * z * (1.0f + copysignf(erf_abs, z));
}

// swizzled LDS address: row stride rb bytes, XOR (row&7)<<4 spreads banks
__device__ __forceinline__ char* lp(void* base, int row, int cb, int rb) {
    return (char*)base + row * rb + (cb ^ ((row & 7) << 4));
}
// 16x32 activation fragment from swizzled LDS (B role): lane -> (x=row, d=kt*32+l4*8+e)
__device__ __forceinline__ h16x8 lda(const void* base, int row, int kt, int rb, int lane) {
    return *(const h16x8*)((const char*)base + row * rb +
                           ((kt * 64 + ((lane >> 4) << 4)) ^ ((row & 7) << 4)));
}
// packed weight fragments: contiguous per fragment, fully coalesced wave reads
__device__ __forceinline__ h16x4 ldp16(const _Float16* w, int frag, int lane) {
    return *(const h16x4*)&w[(frag << 8) + (lane << 2)];
}
__device__ __forceinline__ h16x8 ldp32(const _Float16* w, int frag, int lane) {
    return *(const h16x8*)&w[(frag << 9) + (lane << 3)];
}

__device__ __forceinline__ f32x4 mfma32(h16x8 a, h16x8 b, f32x4 c) {
    return __builtin_amdgcn_mfma_f32_16x16x32_f16(a, b, c, 0, 0, 0);
}
__device__ __forceinline__ f32x4 mfma16(h16x4 a, h16x4 b, f32x4 c) {
    return __builtin_amdgcn_mfma_f32_16x16x16f16(a, b, c, 0, 0, 0);
}

// ---------------- weight prep: fp32 -> packed fp16 fragments ----------------
__global__ __launch_bounds__(256) void k_prep_conv(const float* __restrict__ s,
                                                   _Float16* __restrict__ w) {
    int t = blockIdx.x * 256 + threadIdx.x;
    if (t >= DEPTH * 20480) return;
    int i = t / 20480, r = t % 20480;
    int frag = r >> 9, lane = (r >> 3) & 63, e = r & 7;
    int k = frag >> 3, kt = (frag >> 2) & 1, nt = frag & 3;
    int o = nt * 16 + (lane & 15);
    int d = kt * 32 + ((lane >> 4) << 3) + e;
    w[t] = (_Float16)s[((i * 64 + o) * 64 + d) * 5 + k];
}
__global__ __launch_bounds__(256) void k_pack16(const float* __restrict__ s,
                                                _Float16* __restrict__ w,
                                                int NT, int KT, int K, int total) {
    int t = blockIdx.x * 256 + threadIdx.x;
    if (t >= total) return;
    int per = NT * KT * 256;
    int li = t / per, r = t % per;
    int frag = r >> 8, lane = (r >> 2) & 63, e = r & 3;
    int kt = frag / NT, nt = frag % NT;
    int n = nt * 16 + (lane & 15);
    int kk = kt * 16 + ((lane >> 4) << 2) + e;
    w[t] = (_Float16)s[li * (NT * 16 * K) + n * K + kk];
}

// zero the halo pad rows of both psi buffers (rows 0,1 and X+2,X+3 per batch)
__global__ __launch_bounds__(256) void k_zero_pads(_Float16* __restrict__ pA,
                                                   _Float16* __restrict__ pB) {
    int i = blockIdx.x * 256 + threadIdx.x;      // over B*4*64
    if (i >= B_ * 4 * 64) return;
    int b = i >> 8, r = (i >> 6) & 3, h = i & 63;
    int row = (r < 2) ? r : (X_ + r);            // 0,1,X+2,X+3
    size_t off = ((size_t)b * PROW + row) * H_ + h;
    pA[off] = (_Float16)0.f;
    pB[off] = (_Float16)0.f;
}

// ---------------- encoder (runs once; fp32 VALU, writes fp16 padded psi) ----------------
__global__ __launch_bounds__(256) void k_encoder(const float* __restrict__ xin,
                                                 const float* __restrict__ enc_w,
                                                 const float* __restrict__ enc_b,
                                                 _Float16* __restrict__ psi) {
    const int b  = blockIdx.y;
    const int x0 = blockIdx.x * 64;
    __shared__ float s_x[TIN][64];
    __shared__ float s_w[TIN][H_];
    __shared__ float s_p[64][H_];
    const int tid = threadIdx.x;

    for (int idx = tid; idx < TIN * 64; idx += 256) {
        int t = idx >> 6, xl = idx & 63;
        s_x[t][xl] = xin[((size_t)b * TIN + t) * X_ + x0 + xl];
    }
    for (int idx = tid; idx < TIN * H_; idx += 256) {
        int t = idx >> 6, h = idx & 63;
        s_w[t][h] = enc_w[h * TIN + t];
    }
    __syncthreads();
    {
        int h = tid & 63, grp = tid >> 6;
        float bias = enc_b[h];
        for (int r = 0; r < 16; ++r) {
            int xl = grp * 16 + r;
            float acc = bias;
            #pragma unroll
            for (int t = 0; t < TIN; ++t) acc += s_x[t][xl] * s_w[t][h];
            s_p[xl][h] = acc;
        }
    }
    __syncthreads();
    {
        int lane = tid & 63, wv = tid >> 6;
        for (int r = 0; r < 16; ++r) {
            int xl = wv * 16 + r;
            float v = s_p[xl][lane];
            float s = v;
            #pragma unroll
            for (int off = 32; off; off >>= 1) s += __shfl_xor(s, off);
            float mu = s * (1.0f / 64.0f);
            float dv = v - mu;
            float q = dv * dv;
            #pragma unroll
            for (int off = 32; off; off >>= 1) q += __shfl_xor(q, off);
            float sd = sqrtf(q * (1.0f / 63.0f)) + 1e-6f;
            psi[((size_t)b * PROW + 2 + x0 + xl) * H_ + lane] = (_Float16)(dv / sd);
        }
    }
}

// ---------------- fused layer: round-11 structure + phase-offset weight prefetch ----------------
// psi fp16 padded [b][2|X|2][64]. One tile per block. Register chain
// conv->mlp1->mlp2->LN(->dec head), operand-swapped (D[ch][x] = W.act).
// W1 issued before conv (conv covers L2 latency); W2 issued before gelu
// (gelu's ~1000cy VALU covers); d1 issued before LN.
__global__ __launch_bounds__(256, 3) void k_layer(const _Float16* __restrict__ pin,
                                                  _Float16* __restrict__ pout,
                                                  const _Float16* __restrict__ cw,
                                                  const float* __restrict__ cb,
                                                  const _Float16* __restrict__ w1,
                                                  const float* __restrict__ b1,
                                                  const _Float16* __restrict__ w2,
                                                  const float* __restrict__ b2,
                                                  const float* __restrict__ g,
                                                  const float* __restrict__ bt,
                                                  const _Float16* __restrict__ d1,
                                                  const float* __restrict__ b1d,
                                                  const float* __restrict__ w2d,
                                                  const float* __restrict__ b2d,
                                                  float* __restrict__ yout, int step) {
    __shared__ __align__(16) _Float16 sA[(TILE + 4) * 64];   // 132 rows x 128B = 16.9 KB

    const int tid  = threadIdx.x;
    const int b    = blockIdx.y;
    const int x0   = blockIdx.x * TILE;
    const int lane = tid & 63, wv = tid >> 6;
    const int l15  = lane & 15, l4 = lane >> 4;
    const int XW   = wv * 32;
    const int xg0  = x0 + XW + l15;

    // ---- stage psi rows: padded rows [x0, x0+132) = global x [x0-2, x0+130)
    {
        const _Float16* src = pin + ((size_t)b * PROW + x0) * H_;
        for (int idx = tid; idx < (TILE + 4) * 8; idx += 256) {
            int r = idx >> 3, c8 = idx & 7;
            h16x8 v = *(const h16x8*)(src + r * H_ + c8 * 8);
            *(h16x8*)lp(sA, r, c8 * 16, 128) = v;
        }
    }

    // ---- PREFETCH W1 (all 32 frags, 64 VGPR): conv phase + barrier covers latency
    h16x4 w1r[4][8];
    #pragma unroll
    for (int kt = 0; kt < 4; ++kt)
        #pragma unroll
        for (int ft = 0; ft < 8; ++ft) w1r[kt][ft] = ldp16(w1, kt * 8 + ft, lane);

    __syncthreads();   // the ONLY barrier

    // ---- conv (K=32, swapped): acc[ch][x] over 5 shifts; weights JIT from L2
    f32x4 acc0[4], acc1[4];
    #pragma unroll
    for (int nt = 0; nt < 4; ++nt) {
        acc0[nt] = *(const f32x4*)&cb[nt * 16 + (l4 << 2)];
        acc1[nt] = acc0[nt];
    }
    #pragma unroll
    for (int k = 0; k < K_; ++k) {
        h16x8 b00 = lda(sA, XW + l15 + k,      0, 128, lane);
        h16x8 b01 = lda(sA, XW + l15 + k,      1, 128, lane);
        h16x8 b10 = lda(sA, XW + 16 + l15 + k, 0, 128, lane);
        h16x8 b11 = lda(sA, XW + 16 + l15 + k, 1, 128, lane);
        #pragma unroll
        for (int nt = 0; nt < 4; ++nt) {
            h16x8 a0 = ldp32(cw, (k * 2 + 0) * 4 + nt, lane);
            h16x8 a1 = ldp32(cw, (k * 2 + 1) * 4 + nt, lane);
            acc0[nt] = mfma32(a0, b00, acc0[nt]);
            acc1[nt] = mfma32(a0, b10, acc1[nt]);
            acc0[nt] = mfma32(a1, b01, acc0[nt]);
            acc1[nt] = mfma32(a1, b11, acc1[nt]);
        }
    }
    h16x4 hb0[4], hb1[4];
    #pragma unroll
    for (int nt = 0; nt < 4; ++nt) {
        #pragma unroll
        for (int j = 0; j < 4; ++j) {
            hb0[nt][j] = (_Float16)acc0[nt][j];
            hb1[nt][j] = (_Float16)acc1[nt][j];
        }
    }

    // ---- mlp1 (K=16, swapped): m[f][x] = W1 . h   (weights already in registers)
    f32x4 m0[8], m1[8];
    #pragma unroll
    for (int ft = 0; ft < 8; ++ft) {
        m0[ft] = *(const f32x4*)&b1[ft * 16 + (l4 << 2)];
        m1[ft] = m0[ft];
    }
    #pragma unroll
    for (int kt = 0; kt < 4; ++kt) {
        #pragma unroll
        for (int ft = 0; ft < 8; ++ft) {
            m0[ft] = mfma16(w1r[kt][ft], hb0[kt], m0[ft]);
            m1[ft] = mfma16(w1r[kt][ft], hb1[kt], m1[ft]);
        }
    }

    // ---- PREFETCH W2 (all 32 frags): the gelu VALU block below covers latency
    h16x4 w2r[8][4];
    #pragma unroll
    for (int kt = 0; kt < 8; ++kt)
        #pragma unroll
        for (int nt = 0; nt < 4; ++nt) w2r[kt][nt] = ldp16(w2, kt * 4 + nt, lane);

    // ---- gelu + cvt (long VALU phase)
    h16x4 mb0[8], mb1[8];
    #pragma unroll
    for (int ft = 0; ft < 8; ++ft) {
        #pragma unroll
        for (int j = 0; j < 4; ++j) {
            mb0[ft][j] = (_Float16)gelu_fast(m0[ft][j]);
            mb1[ft][j] = (_Float16)gelu_fast(m1[ft][j]);
        }
    }

    // ---- residual prefetch (fp16 psi; used after mlp2)
    const _Float16* pr0 = pin + ((size_t)b * PROW + 2 + xg0) * H_ + (l4 << 2);
    const _Float16* pr1 = pr0 + 16 * H_;
    f32x4 res0[4], res1[4];
    #pragma unroll
    for (int nt = 0; nt < 4; ++nt) {
        h16x4 r0 = *(const h16x4*)(pr0 + nt * 16);
        h16x4 r1 = *(const h16x4*)(pr1 + nt * 16);
        #pragma unroll
        for (int j = 0; j < 4; ++j) { res0[nt][j] = (float)r0[j]; res1[nt][j] = (float)r1[j]; }
    }

    // ---- mlp2 (K=16, swapped): o[d][x] = W2 . m   (weights already in registers)
    f32x4 o0[4], o1[4];
    #pragma unroll
    for (int nt = 0; nt < 4; ++nt) {
        o0[nt] = *(const f32x4*)&b2[nt * 16 + (l4 << 2)];
        o1[nt] = o0[nt];
    }
    #pragma unroll
    for (int kt = 0; kt < 8; ++kt) {
        #pragma unroll
        for (int nt = 0; nt < 4; ++nt) {
            o0[nt] = mfma16(w2r[kt][nt], mb0[kt], o0[nt]);
            o1[nt] = mfma16(w2r[kt][nt], mb1[kt], o1[nt]);
        }
    }

    // ---- PREFETCH d1 (if decoding): LN VALU block covers latency
    h16x4 d1r[4][4];
    if (yout) {
        #pragma unroll
        for (int kt = 0; kt < 4; ++kt)
            #pragma unroll
            for (int ht = 0; ht < 4; ++ht) d1r[kt][ht] = ldp16(d1, kt * 4 + ht, lane);
    }

    // ---- residual + LN + clip + fp16 store; ps regs feed dec head
    _Float16* pw0 = pout + ((size_t)b * PROW + 2 + xg0) * H_ + (l4 << 2);
    _Float16* pw1 = pw0 + 16 * H_;
    h16x4 ps0[4], ps1[4];
#define LN_CG(OACC, RES, PW, PS)                                               \
    {                                                                          \
        float v[4][4];                                                         \
        float s = 0.f;                                                         \
        _Pragma("unroll")                                                      \
        for (int nt = 0; nt < 4; ++nt) {                                       \
            _Pragma("unroll")                                                  \
            for (int j = 0; j < 4; ++j) {                                      \
                v[nt][j] = OACC[nt][j] + RES[nt][j]; s += v[nt][j];            \
            }                                                                  \
        }                                                                      \
        s += __shfl_xor(s, 16); s += __shfl_xor(s, 32);                        \
        float mu = s * (1.0f / 64.0f);                                         \
        float q = 0.f;                                                         \
        _Pragma("unroll")                                                      \
        for (int nt = 0; nt < 4; ++nt) {                                       \
            _Pragma("unroll")                                                  \
            for (int j = 0; j < 4; ++j) { v[nt][j] -= mu; q += v[nt][j] * v[nt][j]; } \
        }                                                                      \
        q += __shfl_xor(q, 16); q += __shfl_xor(q, 32);                        \
        float rs = rsqrtf(q * (1.0f / 64.0f) + 1e-5f);                         \
        _Pragma("unroll")                                                      \
        for (int nt = 0; nt < 4; ++nt) {                                       \
            f32x4 gg = *(const f32x4*)&g[nt * 16 + (l4 << 2)];                 \
            f32x4 bb = *(const f32x4*)&bt[nt * 16 + (l4 << 2)];                \
            _Pragma("unroll")                                                  \
            for (int j = 0; j < 4; ++j) {                                      \
                float o = v[nt][j] * rs * gg[j] + bb[j];                       \
                o = fminf(10.0f, fmaxf(-10.0f, o));                            \
                PS[nt][j] = (_Float16)o;                                       \
            }                                                                  \
            *(h16x4*)(PW + nt * 16) = PS[nt];                                  \
        }                                                                      \
    }
    LN_CG(o0, res0, pw0, ps0)
    LN_CG(o1, res1, pw1, ps1)
#undef LN_CG

    // ---- fused decoder head (depth 2 only; d1 already in registers)
    if (yout) {
        f32x4 d0[4], dd1[4];
        #pragma unroll
        for (int ht = 0; ht < 4; ++ht) {
            d0[ht] = *(const f32x4*)&b1d[ht * 16 + (l4 << 2)];
            dd1[ht] = d0[ht];
        }
        #pragma unroll
        for (int kt = 0; kt < 4; ++kt) {
            #pragma unroll
            for (int ht = 0; ht < 4; ++ht) {
                d0[ht]  = mfma16(d1r[kt][ht], ps0[kt], d0[ht]);
                dd1[ht] = mfma16(d1r[kt][ht], ps1[kt], dd1[ht]);
            }
        }
        float y0 = 0.f, y1 = 0.f;
        #pragma unroll
        for (int ht = 0; ht < 4; ++ht) {
            f32x4 wq = *(const f32x4*)&w2d[ht * 16 + (l4 << 2)];
            #pragma unroll
            for (int j = 0; j < 4; ++j) {
                y0 += gelu_fast(d0[ht][j])  * wq[j];
                y1 += gelu_fast(dd1[ht][j]) * wq[j];
            }
        }
        y0 += __shfl_xor(y0, 16); y0 += __shfl_xor(y0, 32);
        y1 += __shfl_xor(y1, 16); y1 += __shfl_xor(y1, 32);
        if (l4 == 0) {
            size_t ybase = ((size_t)b * TOUT + step) * X_;
            yout[ybase + xg0]      = y0 + b2d[0];
            yout[ybase + xg0 + 16] = y1 + b2d[0];
        }
    }
}

extern "C" void kernel_launch(void* const* d_in, const int* in_sizes, int n_in,
                              void* d_out, int out_size, void* d_ws, size_t ws_size,
                              hipStream_t stream) {
    const float* xin    = (const float*)d_in[0];
    const float* enc_w  = (const float*)d_in[1];
    const float* enc_b  = (const float*)d_in[2];
    const float* conv_w = (const float*)d_in[3];
    const float* conv_b = (const float*)d_in[4];
    const float* mlp_w1 = (const float*)d_in[5];
    const float* mlp_b1 = (const float*)d_in[6];
    const float* mlp_w2 = (const float*)d_in[7];
    const float* mlp_b2 = (const float*)d_in[8];
    const float* ln_g   = (const float*)d_in[9];
    const float* ln_b   = (const float*)d_in[10];
    const float* dec_w1 = (const float*)d_in[11];
    const float* dec_b1 = (const float*)d_in[12];
    const float* dec_w2 = (const float*)d_in[13];
    const float* dec_b2 = (const float*)d_in[14];
    float* out = (float*)d_out;

    const size_t PSI = (size_t)B_ * PROW * H_;       // fp16 elements
    _Float16* psiA = (_Float16*)d_ws;
    _Float16* psiB = psiA + PSI;
    _Float16* cwf = psiB + PSI;               // [3][40 frags][512]
    _Float16* w1f = cwf + 61440;              // [3][32 frags][256]
    _Float16* w2f = w1f + 24576;              // [3][32 frags][256]
    _Float16* d1f = w2f + 24576;              // [16 frags][256]
    (void)ws_size; (void)n_in; (void)in_sizes; (void)out_size;

    k_zero_pads<<<32, 256, 0, stream>>>(psiA, psiB);
    k_prep_conv<<<240, 256, 0, stream>>>(conv_w, cwf);
    k_pack16<<<96, 256, 0, stream>>>(mlp_w1, w1f, 8, 4, 64, 24576);
    k_pack16<<<96, 256, 0, stream>>>(mlp_w2, w2f, 4, 8, 128, 24576);
    k_pack16<<<16, 256, 0, stream>>>(dec_w1, d1f, 4, 4, 64, 4096);

    k_encoder<<<dim3(X_ / 64, B_), 256, 0, stream>>>(xin, enc_w, enc_b, psiA);

    const _Float16* cur = psiA;
    _Float16* nxt = psiB;
    for (int t = 0; t < TOUT; ++t) {
        for (int i = 0; i < DEPTH; ++i) {
            float* yout = (i == DEPTH - 1) ? out : nullptr;
            k_layer<<<dim3(X_ / TILE, B_), 256, 0, stream>>>(
                cur, nxt,
                cwf + i * 20480, conv_b + i * H_,
                w1f + i * 8192,  mlp_b1 + i * F_,
                w2f + i * 8192,  mlp_b2 + i * H_,
                ln_g + i * H_, ln_b + i * H_,
                d1f, dec_b1, dec_w2, dec_b2, yout, t);
            _Float16* tmp = (_Float16*)cur; cur = nxt; nxt = tmp;
        }
    }
}

// Round 14
// 5458.318 us; speedup vs baseline: 2.9973x; 1.2946x over previous
//
#include <hip/hip_runtime.h>
#include <hip/hip_bf16.h>

#define B_   32
#define TIN  16
#define X_   8192
#define H_   64
#define F_   128
#define K_   5
#define DEPTH 3
#define TOUT 32
#define TILE 256          // 4 waves x 64 x-columns (4 col-groups each)
#define PROW (X_ + 4)     // padded rows per batch: 2 zero | X | 2 zero

typedef __attribute__((ext_vector_type(8))) _Float16 h16x8;
typedef __attribute__((ext_vector_type(4))) _Float16 h16x4;
typedef __attribute__((ext_vector_type(4))) float f32x4;

// GELU via A&S 7.1.25 3-term erf (|eps| <= 2.5e-5), branch-free
__device__ __forceinline__ float gelu_fast(float z) {
    float t = fminf(fabsf(z) * 0.70710678118654752f, 3.9192f);
    float w = __builtin_amdgcn_rcpf(__builtin_fmaf(0.47047f, t, 1.0f));
    float p = w * __builtin_fmaf(w, __builtin_fmaf(w, 0.7478556f, -0.0958798f), 0.3480242f);
    float e = __expf(-t * t);
    float erf_abs = __builtin_fmaf(-p, e, 1.0f);
    return 0.5f * z * (1.0f + copysignf(erf_abs, z));
}

// swizzled LDS address: row stride rb bytes, XOR (row&7)<<4 spreads banks
__device__ __forceinline__ char* lp(void* base, int row, int cb, int rb) {
    return (char*)base + row * rb + (cb ^ ((row & 7) << 4));
}
// 16x32 activation fragment from swizzled LDS (B role): lane -> (x=row, d=kt*32+l4*8+e)
__device__ __forceinline__ h16x8 lda(const void* base, int row, int kt, int rb, int lane) {
    return *(const h16x8*)((const char*)base + row * rb +
                           ((kt * 64 + ((lane >> 4) << 4)) ^ ((row & 7) << 4)));
}
// packed weight fragments: contiguous per fragment, fully coalesced wave reads
__device__ __forceinline__ h16x4 ldp16(const _Float16* w, int frag, int lane) {
    return *(const h16x4*)&w[(frag << 8) + (lane << 2)];
}
__device__ __forceinline__ h16x8 ldp32(const _Float16* w, int frag, int lane) {
    return *(const h16x8*)&w[(frag << 9) + (lane << 3)];
}

__device__ __forceinline__ f32x4 mfma32(h16x8 a, h16x8 b, f32x4 c) {
    return __builtin_amdgcn_mfma_f32_16x16x32_f16(a, b, c, 0, 0, 0);
}
__device__ __forceinline__ f32x4 mfma16(h16x4 a, h16x4 b, f32x4 c) {
    return __builtin_amdgcn_mfma_f32_16x16x16f16(a, b, c, 0, 0, 0);
}

// ---------------- weight prep: fp32 -> packed fp16 fragments ----------------
__global__ __launch_bounds__(256) void k_prep_conv(const float* __restrict__ s,
                                                   _Float16* __restrict__ w) {
    int t = blockIdx.x * 256 + threadIdx.x;
    if (t >= DEPTH * 20480) return;
    int i = t / 20480, r = t % 20480;
    int frag = r >> 9, lane = (r >> 3) & 63, e = r & 7;
    int k = frag >> 3, kt = (frag >> 2) & 1, nt = frag & 3;
    int o = nt * 16 + (lane & 15);
    int d = kt * 32 + ((lane >> 4) << 3) + e;
    w[t] = (_Float16)s[((i * 64 + o) * 64 + d) * 5 + k];
}
__global__ __launch_bounds__(256) void k_pack16(const float* __restrict__ s,
                                                _Float16* __restrict__ w,
                                                int NT, int KT, int K, int total) {
    int t = blockIdx.x * 256 + threadIdx.x;
    if (t >= total) return;
    int per = NT * KT * 256;
    int li = t / per, r = t % per;
    int frag = r >> 8, lane = (r >> 2) & 63, e = r & 3;
    int kt = frag / NT, nt = frag % NT;
    int n = nt * 16 + (lane & 15);
    int kk = kt * 16 + ((lane >> 4) << 2) + e;
    w[t] = (_Float16)s[li * (NT * 16 * K) + n * K + kk];
}

// zero the halo pad rows of both psi buffers (rows 0,1 and X+2,X+3 per batch)
__global__ __launch_bounds__(256) void k_zero_pads(_Float16* __restrict__ pA,
                                                   _Float16* __restrict__ pB) {
    int i = blockIdx.x * 256 + threadIdx.x;      // over B*4*64
    if (i >= B_ * 4 * 64) return;
    int b = i >> 8, r = (i >> 6) & 3, h = i & 63;
    int row = (r < 2) ? r : (X_ + r);            // 0,1,X+2,X+3
    size_t off = ((size_t)b * PROW + row) * H_ + h;
    pA[off] = (_Float16)0.f;
    pB[off] = (_Float16)0.f;
}

// ---------------- encoder (runs once; fp32 VALU, writes fp16 padded psi) ----------------
__global__ __launch_bounds__(256) void k_encoder(const float* __restrict__ xin,
                                                 const float* __restrict__ enc_w,
                                                 const float* __restrict__ enc_b,
                                                 _Float16* __restrict__ psi) {
    const int b  = blockIdx.y;
    const int x0 = blockIdx.x * 64;
    __shared__ float s_x[TIN][64];
    __shared__ float s_w[TIN][H_];
    __shared__ float s_p[64][H_];
    const int tid = threadIdx.x;

    for (int idx = tid; idx < TIN * 64; idx += 256) {
        int t = idx >> 6, xl = idx & 63;
        s_x[t][xl] = xin[((size_t)b * TIN + t) * X_ + x0 + xl];
    }
    for (int idx = tid; idx < TIN * H_; idx += 256) {
        int t = idx >> 6, h = idx & 63;
        s_w[t][h] = enc_w[h * TIN + t];
    }
    __syncthreads();
    {
        int h = tid & 63, grp = tid >> 6;
        float bias = enc_b[h];
        for (int r = 0; r < 16; ++r) {
            int xl = grp * 16 + r;
            float acc = bias;
            #pragma unroll
            for (int t = 0; t < TIN; ++t) acc += s_x[t][xl] * s_w[t][h];
            s_p[xl][h] = acc;
        }
    }
    __syncthreads();
    {
        int lane = tid & 63, wv = tid >> 6;
        for (int r = 0; r < 16; ++r) {
            int xl = wv * 16 + r;
            float v = s_p[xl][lane];
            float s = v;
            #pragma unroll
            for (int off = 32; off; off >>= 1) s += __shfl_xor(s, off);
            float mu = s * (1.0f / 64.0f);
            float dv = v - mu;
            float q = dv * dv;
            #pragma unroll
            for (int off = 32; off; off >>= 1) q += __shfl_xor(q, off);
            float sd = sqrtf(q * (1.0f / 63.0f)) + 1e-6f;
            psi[((size_t)b * PROW + 2 + x0 + xl) * H_ + lane] = (_Float16)(dv / sd);
        }
    }
}

// ---------------- fused layer: M=64/wave (4 col-groups), register chain ----------------
// psi fp16 padded [b][2|X|2][64]. One tile per block (TILE=256, 4 waves x 64 cols).
// Every weight fragment feeds 4 independent MFMAs (4 cgs) -> half the L2
// loads per FLOP of M=32 and 4 independent dep-chains per wave for ILP.
__global__ __launch_bounds__(256, 2) void k_layer(const _Float16* __restrict__ pin,
                                                  _Float16* __restrict__ pout,
                                                  const _Float16* __restrict__ cw,
                                                  const float* __restrict__ cb,
                                                  const _Float16* __restrict__ w1,
                                                  const float* __restrict__ b1,
                                                  const _Float16* __restrict__ w2,
                                                  const float* __restrict__ b2,
                                                  const float* __restrict__ g,
                                                  const float* __restrict__ bt,
                                                  const _Float16* __restrict__ d1,
                                                  const float* __restrict__ b1d,
                                                  const float* __restrict__ w2d,
                                                  const float* __restrict__ b2d,
                                                  float* __restrict__ yout, int step) {
    __shared__ __align__(16) _Float16 sA[(TILE + 4) * 64];   // 260 rows x 128B = 33.3 KB

    const int tid  = threadIdx.x;
    const int b    = blockIdx.y;
    const int x0   = blockIdx.x * TILE;
    const int lane = tid & 63, wv = tid >> 6;
    const int l15  = lane & 15, l4 = lane >> 4;
    const int XW   = wv * 64;                 // wave owns 64 x-columns
    const int xg0  = x0 + XW + l15;

    // ---- stage psi rows: padded rows [x0, x0+260) = global x [x0-2, x0+258)
    {
        const _Float16* src = pin + ((size_t)b * PROW + x0) * H_;
        for (int idx = tid; idx < (TILE + 4) * 8; idx += 256) {
            int r = idx >> 3, c8 = idx & 7;
            h16x8 v = *(const h16x8*)(src + r * H_ + c8 * 8);
            *(h16x8*)lp(sA, r, c8 * 16, 128) = v;
        }
    }
    __syncthreads();   // the ONLY barrier

    // ---- conv (K=32, swapped): acc[cg][nt]; each weight frag feeds 4 cgs
    f32x4 acc[4][4];
    #pragma unroll
    for (int nt = 0; nt < 4; ++nt) {
        f32x4 bb = *(const f32x4*)&cb[nt * 16 + (l4 << 2)];
        #pragma unroll
        for (int cg = 0; cg < 4; ++cg) acc[cg][nt] = bb;
    }
    #pragma unroll
    for (int k = 0; k < K_; ++k) {
        h16x8 bfrag[4][2];
        #pragma unroll
        for (int cg = 0; cg < 4; ++cg) {
            bfrag[cg][0] = lda(sA, XW + cg * 16 + l15 + k, 0, 128, lane);
            bfrag[cg][1] = lda(sA, XW + cg * 16 + l15 + k, 1, 128, lane);
        }
        #pragma unroll
        for (int nt = 0; nt < 4; ++nt) {
            h16x8 a0 = ldp32(cw, (k * 2 + 0) * 4 + nt, lane);
            h16x8 a1 = ldp32(cw, (k * 2 + 1) * 4 + nt, lane);
            #pragma unroll
            for (int cg = 0; cg < 4; ++cg) {
                acc[cg][nt] = mfma32(a0, bfrag[cg][0], acc[cg][nt]);
                acc[cg][nt] = mfma32(a1, bfrag[cg][1], acc[cg][nt]);
            }
        }
    }
    h16x4 hb[4][4];
    #pragma unroll
    for (int cg = 0; cg < 4; ++cg)
        #pragma unroll
        for (int nt = 0; nt < 4; ++nt) {
            #pragma unroll
            for (int j = 0; j < 4; ++j) hb[cg][nt][j] = (_Float16)acc[cg][nt][j];
        }

    // ---- mlp1 (K=16, swapped): m[f][x] = W1 . h ; each frag feeds 4 cgs
    f32x4 m[4][8];
    #pragma unroll
    for (int ft = 0; ft < 8; ++ft) {
        f32x4 bb = *(const f32x4*)&b1[ft * 16 + (l4 << 2)];
        #pragma unroll
        for (int cg = 0; cg < 4; ++cg) m[cg][ft] = bb;
    }
    #pragma unroll
    for (int kt = 0; kt < 4; ++kt) {
        #pragma unroll
        for (int ft = 0; ft < 8; ++ft) {
            h16x4 aw = ldp16(w1, kt * 8 + ft, lane);
            #pragma unroll
            for (int cg = 0; cg < 4; ++cg) m[cg][ft] = mfma16(aw, hb[cg][kt], m[cg][ft]);
        }
    }

    // ---- gelu + cvt (long VALU phase); m dies here
    h16x4 mb[4][8];
    #pragma unroll
    for (int cg = 0; cg < 4; ++cg)
        #pragma unroll
        for (int ft = 0; ft < 8; ++ft) {
            #pragma unroll
            for (int j = 0; j < 4; ++j) mb[cg][ft][j] = (_Float16)gelu_fast(m[cg][ft][j]);
        }

    // ---- residual prefetch (after gelu to cap register peak)
    f32x4 res[4][4];
    #pragma unroll
    for (int cg = 0; cg < 4; ++cg) {
        const _Float16* pr = pin + ((size_t)b * PROW + 2 + xg0 + cg * 16) * H_ + (l4 << 2);
        #pragma unroll
        for (int nt = 0; nt < 4; ++nt) {
            h16x4 r0 = *(const h16x4*)(pr + nt * 16);
            #pragma unroll
            for (int j = 0; j < 4; ++j) res[cg][nt][j] = (float)r0[j];
        }
    }

    // ---- mlp2 (K=16, swapped): o[d][x] = W2 . m ; each frag feeds 4 cgs
    f32x4 o[4][4];
    #pragma unroll
    for (int nt = 0; nt < 4; ++nt) {
        f32x4 bb = *(const f32x4*)&b2[nt * 16 + (l4 << 2)];
        #pragma unroll
        for (int cg = 0; cg < 4; ++cg) o[cg][nt] = bb;
    }
    #pragma unroll
    for (int kt = 0; kt < 8; ++kt) {
        #pragma unroll
        for (int nt = 0; nt < 4; ++nt) {
            h16x4 aw = ldp16(w2, kt * 4 + nt, lane);
            #pragma unroll
            for (int cg = 0; cg < 4; ++cg) o[cg][nt] = mfma16(aw, mb[cg][kt], o[cg][nt]);
        }
    }

    // ---- residual + LN + clip + fp16 store; ps regs feed dec head
    h16x4 ps[4][4];
    #pragma unroll
    for (int cg = 0; cg < 4; ++cg) {
        float v[4][4];
        float s = 0.f;
        #pragma unroll
        for (int nt = 0; nt < 4; ++nt) {
            #pragma unroll
            for (int j = 0; j < 4; ++j) { v[nt][j] = o[cg][nt][j] + res[cg][nt][j]; s += v[nt][j]; }
        }
        s += __shfl_xor(s, 16); s += __shfl_xor(s, 32);
        float mu = s * (1.0f / 64.0f);
        float q = 0.f;
        #pragma unroll
        for (int nt = 0; nt < 4; ++nt) {
            #pragma unroll
            for (int j = 0; j < 4; ++j) { v[nt][j] -= mu; q += v[nt][j] * v[nt][j]; }
        }
        q += __shfl_xor(q, 16); q += __shfl_xor(q, 32);
        float rs = rsqrtf(q * (1.0f / 64.0f) + 1e-5f);
        _Float16* pw = pout + ((size_t)b * PROW + 2 + xg0 + cg * 16) * H_ + (l4 << 2);
        #pragma unroll
        for (int nt = 0; nt < 4; ++nt) {
            f32x4 gg = *(const f32x4*)&g[nt * 16 + (l4 << 2)];
            f32x4 bb = *(const f32x4*)&bt[nt * 16 + (l4 << 2)];
            #pragma unroll
            for (int j = 0; j < 4; ++j) {
                float ov = v[nt][j] * rs * gg[j] + bb[j];
                ov = fminf(10.0f, fmaxf(-10.0f, ov));
                ps[cg][nt][j] = (_Float16)ov;
            }
            *(h16x4*)(pw + nt * 16) = ps[cg][nt];
        }
    }

    // ---- fused decoder head (depth 2 only)
    if (yout) {
        f32x4 dacc[4][4];
        #pragma unroll
        for (int ht = 0; ht < 4; ++ht) {
            f32x4 bb = *(const f32x4*)&b1d[ht * 16 + (l4 << 2)];
            #pragma unroll
            for (int cg = 0; cg < 4; ++cg) dacc[cg][ht] = bb;
        }
        #pragma unroll
        for (int kt = 0; kt < 4; ++kt) {
            #pragma unroll
            for (int ht = 0; ht < 4; ++ht) {
                h16x4 aw = ldp16(d1, kt * 4 + ht, lane);
                #pragma unroll
                for (int cg = 0; cg < 4; ++cg) dacc[cg][ht] = mfma16(aw, ps[cg][kt], dacc[cg][ht]);
            }
        }
        float y[4] = {0.f, 0.f, 0.f, 0.f};
        #pragma unroll
        for (int ht = 0; ht < 4; ++ht) {
            f32x4 wq = *(const f32x4*)&w2d[ht * 16 + (l4 << 2)];
            #pragma unroll
            for (int cg = 0; cg < 4; ++cg) {
                #pragma unroll
                for (int j = 0; j < 4; ++j) y[cg] += gelu_fast(dacc[cg][ht][j]) * wq[j];
            }
        }
        #pragma unroll
        for (int cg = 0; cg < 4; ++cg) {
            y[cg] += __shfl_xor(y[cg], 16);
            y[cg] += __shfl_xor(y[cg], 32);
        }
        if (l4 == 0) {
            size_t ybase = ((size_t)b * TOUT + step) * X_;
            #pragma unroll
            for (int cg = 0; cg < 4; ++cg)
                yout[ybase + xg0 + cg * 16] = y[cg] + b2d[0];
        }
    }
}

extern "C" void kernel_launch(void* const* d_in, const int* in_sizes, int n_in,
                              void* d_out, int out_size, void* d_ws, size_t ws_size,
                              hipStream_t stream) {
    const float* xin    = (const float*)d_in[0];
    const float* enc_w  = (const float*)d_in[1];
    const float* enc_b  = (const float*)d_in[2];
    const float* conv_w = (const float*)d_in[3];
    const float* conv_b = (const float*)d_in[4];
    const float* mlp_w1 = (const float*)d_in[5];
    const float* mlp_b1 = (const float*)d_in[6];
    const float* mlp_w2 = (const float*)d_in[7];
    const float* mlp_b2 = (const float*)d_in[8];
    const float* ln_g   = (const float*)d_in[9];
    const float* ln_b   = (const float*)d_in[10];
    const float* dec_w1 = (const float*)d_in[11];
    const float* dec_b1 = (const float*)d_in[12];
    const float* dec_w2 = (const float*)d_in[13];
    const float* dec_b2 = (const float*)d_in[14];
    float* out = (float*)d_out;

    const size_t PSI = (size_t)B_ * PROW * H_;       // fp16 elements
    _Float16* psiA = (_Float16*)d_ws;
    _Float16* psiB = psiA + PSI;
    _Float16* cwf = psiB + PSI;               // [3][40 frags][512]
    _Float16* w1f = cwf + 61440;              // [3][32 frags][256]
    _Float16* w2f = w1f + 24576;              // [3][32 frags][256]
    _Float16* d1f = w2f + 24576;              // [16 frags][256]
    (void)ws_size; (void)n_in; (void)in_sizes; (void)out_size;

    k_zero_pads<<<32, 256, 0, stream>>>(psiA, psiB);
    k_prep_conv<<<240, 256, 0, stream>>>(conv_w, cwf);
    k_pack16<<<96, 256, 0, stream>>>(mlp_w1, w1f, 8, 4, 64, 24576);
    k_pack16<<<96, 256, 0, stream>>>(mlp_w2, w2f, 4, 8, 128, 24576);
    k_pack16<<<16, 256, 0, stream>>>(dec_w1, d1f, 4, 4, 64, 4096);

    k_encoder<<<dim3(X_ / 64, B_), 256, 0, stream>>>(xin, enc_w, enc_b, psiA);

    const _Float16* cur = psiA;
    _Float16* nxt = psiB;
    for (int t = 0; t < TOUT; ++t) {
        for (int i = 0; i < DEPTH; ++i) {
            float* yout = (i == DEPTH - 1) ? out : nullptr;
            k_layer<<<dim3(X_ / TILE, B_), 256, 0, stream>>>(
                cur, nxt,
                cwf + i * 20480, conv_b + i * H_,
                w1f + i * 8192,  mlp_b1 + i * F_,
                w2f + i * 8192,  mlp_b2 + i * H_,
                ln_g + i * H_, ln_b + i * H_,
                d1f, dec_b1, dec_w2, dec_b2, yout, t);
            _Float16* tmp = (_Float16*)cur; cur = nxt; nxt = tmp;
        }
    }
}